// Round 1
// baseline (773.255 us; speedup 1.0000x reference)
//
#include <hip/hip_runtime.h>

// AtlasAttention: out = MLP2(relu(MLP1(poly(clip(X@Wq))))) [:, :64], heads folded.
// Shapes: X[8192,768] fp32, Wq[768,768], W1[256,512], b1[512], W2[512,256], b2[256].
// rows = 98304 (token*12+head). q flat layout == out flat layout == [row*64+d],
// so q is staged in d_out and overwritten chunk-by-chunk by the final GEMM.

#define BM 64
#define BN 64
#define BK 16

// 256 threads: loader A: ar=tid>>2 (row 0..63), akq=tid&3 (k-quad)
//              loader B: br=tid>>4 (k 0..15),  bcq=tid&15 (n-quad)
// compute: tx=tid&15 (4 cols each), ty=tid>>4 (4 rows each)
template<bool POLY, bool RELU, bool BIAS>
__global__ __launch_bounds__(256)
void gemm_k(const float* __restrict__ A, const float* __restrict__ B,
            const float* __restrict__ bias, const float* __restrict__ coeffs,
            float* __restrict__ C, int M, int N, int K,
            int lda, int ldb, int ldc)
{
    __shared__ float As[BK][BM + 4];   // stored transposed: As[k][m]
    __shared__ float Bs[BK][BN + 4];

    const int tid = threadIdx.x;
    const int bm = blockIdx.x * BM;
    const int bn = blockIdx.y * BN;
    const int tx = tid & 15, ty = tid >> 4;
    const int ar = tid >> 2, akq = tid & 3;
    const int br = tid >> 4, bcq = tid & 15;

    float c0 = 0.f, c1 = 0.f, c2 = 0.f, c3 = 0.f;
    if constexpr (POLY) {
        c0 = coeffs[0]; c1 = coeffs[1]; c2 = coeffs[2]; c3 = coeffs[3];
    }

    float acc[4][4];
    #pragma unroll
    for (int i = 0; i < 4; ++i)
        #pragma unroll
        for (int j = 0; j < 4; ++j) acc[i][j] = 0.f;

    for (int k0 = 0; k0 < K; k0 += BK) {
        // ---- stage A tile (optionally polynomial-expanded from q) ----
        float4 av;
        if constexpr (POLY) {
            // logical A[row][k]: oct = k>>6 (wave-uniform per tile), d = k&63
            const int kk = k0 + (akq << 2);
            const int oct = kk >> 6;
            const int d = kk & 63;
            const float4 qv = *reinterpret_cast<const float4*>(
                A + (size_t)(bm + ar) * lda + d);
            const float c = (oct == 0) ? c0 : (oct == 1) ? c1 : (oct == 2) ? c2 : c3;
            float xv[4] = {qv.x, qv.y, qv.z, qv.w};
            float fv[4];
            #pragma unroll
            for (int i = 0; i < 4; ++i) {
                float x = fminf(fmaxf(xv[i], -10.f), 10.f);
                float p = 1.f;
                if (oct >= 1) p = x;
                if (oct >= 2) p *= x;
                if (oct == 3) p *= x;
                float v = c * p;
                fv[i] = (oct == 0) ? c : fminf(fmaxf(v, -1e6f), 1e6f);
            }
            av = make_float4(fv[0], fv[1], fv[2], fv[3]);
        } else {
            av = *reinterpret_cast<const float4*>(
                A + (size_t)(bm + ar) * lda + k0 + (akq << 2));
        }
        As[(akq << 2) + 0][ar] = av.x;
        As[(akq << 2) + 1][ar] = av.y;
        As[(akq << 2) + 2][ar] = av.z;
        As[(akq << 2) + 3][ar] = av.w;

        // ---- stage B tile ----
        const float4 bv = *reinterpret_cast<const float4*>(
            B + (size_t)(k0 + br) * ldb + bn + (bcq << 2));
        *reinterpret_cast<float4*>(&Bs[br][bcq << 2]) = bv;

        __syncthreads();

        #pragma unroll
        for (int kk = 0; kk < BK; ++kk) {
            const float4 a = *reinterpret_cast<const float4*>(&As[kk][ty << 2]);
            const float4 b = *reinterpret_cast<const float4*>(&Bs[kk][tx << 2]);
            const float am[4] = {a.x, a.y, a.z, a.w};
            const float bm_[4] = {b.x, b.y, b.z, b.w};
            #pragma unroll
            for (int i = 0; i < 4; ++i)
                #pragma unroll
                for (int j = 0; j < 4; ++j)
                    acc[i][j] = fmaf(am[i], bm_[j], acc[i][j]);
        }
        __syncthreads();
    }

    // ---- epilogue ----
    float bb[4] = {0.f, 0.f, 0.f, 0.f};
    if constexpr (BIAS) {
        #pragma unroll
        for (int j = 0; j < 4; ++j) bb[j] = bias[bn + (tx << 2) + j];
    }
    #pragma unroll
    for (int i = 0; i < 4; ++i) {
        const int row = bm + (ty << 2) + i;
        float4 v = make_float4(acc[i][0], acc[i][1], acc[i][2], acc[i][3]);
        if constexpr (BIAS) { v.x += bb[0]; v.y += bb[1]; v.z += bb[2]; v.w += bb[3]; }
        if constexpr (RELU) {
            v.x = fmaxf(v.x, 0.f); v.y = fmaxf(v.y, 0.f);
            v.z = fmaxf(v.z, 0.f); v.w = fmaxf(v.w, 0.f);
        }
        *reinterpret_cast<float4*>(C + (size_t)row * ldc + bn + (tx << 2)) = v;
    }
}

extern "C" void kernel_launch(void* const* d_in, const int* in_sizes, int n_in,
                              void* d_out, int out_size, void* d_ws, size_t ws_size,
                              hipStream_t stream) {
    const float* X      = (const float*)d_in[0];   // [8192, 768]
    const float* Wq     = (const float*)d_in[1];   // [768, 768]
    const float* coeffs = (const float*)d_in[2];   // [4]
    const float* W1     = (const float*)d_in[3];   // [256, 512]
    const float* b1     = (const float*)d_in[4];   // [512]
    const float* W2     = (const float*)d_in[5];   // [512, 256]
    const float* b2     = (const float*)d_in[6];   // [256]
    float* out = (float*)d_out;                    // [8192, 768] == q staging == final
    float* H   = (float*)d_ws;                     // [CH, 512] scratch

    // GEMM1: q = X @ Wq  -> staged directly in d_out (same flat layout as final out)
    gemm_k<false, false, false><<<dim3(8192 / BM, 768 / BN), 256, 0, stream>>>(
        X, Wq, nullptr, nullptr, out, 8192, 768, 768, 768, 768, 768);

    const long ROWS = 98304;  // 8192 tokens * 12 heads
    long ch = (long)(ws_size / (512 * sizeof(float)));
    ch -= ch % BM;
    if (ch > 16384) ch = 16384;   // keep H chunk (~33 MB) L3-resident
    if (ch < BM) ch = BM;

    for (long r0 = 0; r0 < ROWS; r0 += ch) {
        const long rows = (ROWS - r0 < ch) ? (ROWS - r0) : ch;
        // GEMM2 (poly-fused A): H = relu(poly(q_chunk) @ W1 + b1)
        gemm_k<true, true, true><<<dim3(rows / BM, 512 / BN), 256, 0, stream>>>(
            out + r0 * 64, W1, b1, coeffs, H,
            (int)rows, 512, 256, 64, 512, 512);
        // GEMM3: out_chunk = H @ W2[:, :64] + b2[:64]  (overwrites consumed q rows)
        gemm_k<false, false, true><<<dim3(rows / BM, 64 / BN), 256, 0, stream>>>(
            H, W2, b2, nullptr, out + r0 * 64,
            (int)rows, 64, 512, 512, 256, 64);
    }
}

// Round 2
// 185.430 us; speedup vs baseline: 4.1701x; 4.1701x over previous
//
#include <hip/hip_runtime.h>

// AtlasAttention bf16-MFMA version.
// out = MLP2(relu(MLP1(poly(clip(X@Wq)))))[:, :64], heads folded.
// X[8192,768] fp32, Wq[768,768], W1[256,512], W2[512,256] (only first 64 cols used).
// rows = 98304 (token*12+head); q flat layout == out flat layout == [row*64+d],
// so q (fp32) is staged in d_out and overwritten chunk-by-chunk by gemm3.
//
// ws layout (bytes):
//   Xb   @ 0          : 8192*768 bf16   = 12,582,912
//   Wqb  @ 12,582,912 : 768*768  bf16^T = 1,179,648   (Wqb[n][k])
//   W1b  @ 13,762,560 : 512*256  bf16^T = 262,144     (W1b[n][k])
//   W2b  @ 14,024,704 : 64*512   bf16^T = 65,536      (W2b[n][k], first 64 cols)
//   Hb   @ 14,090,240 : chunk rows * 512 bf16

typedef unsigned short u16;
typedef __attribute__((ext_vector_type(8))) short short8;
typedef __attribute__((ext_vector_type(4))) float f32x4;
typedef __attribute__((ext_vector_type(4))) u16 u16x4;

__device__ __forceinline__ u16 f2bf(float f) {
    unsigned u = __builtin_bit_cast(unsigned, f);
    u += 0x7FFFu + ((u >> 16) & 1u);   // RNE
    return (u16)(u >> 16);
}

__device__ __forceinline__ void gl2lds16(const void* g, void* l) {
    __builtin_amdgcn_global_load_lds(
        (const __attribute__((address_space(1))) unsigned int*)g,
        (__attribute__((address_space(3))) unsigned int*)l, 16, 0, 0);
}

// ---------------- conversion kernels ----------------

__global__ __launch_bounds__(256) void cast_f32_bf16(const float* __restrict__ in,
                                                     u16* __restrict__ out, int n4) {
    int i = blockIdx.x * 256 + threadIdx.x;
    if (i < n4) {
        float4 v = reinterpret_cast<const float4*>(in)[i];
        u16x4 o = {f2bf(v.x), f2bf(v.y), f2bf(v.z), f2bf(v.w)};
        reinterpret_cast<u16x4*>(out)[i] = o;
    }
}

// in: [R][Cin] fp32; out: [C][R] bf16 (first C cols of in). grid (C/32, R/32), block (32,8).
__global__ __launch_bounds__(256) void transpose_cast(const float* __restrict__ in,
                                                      u16* __restrict__ out,
                                                      int R, int Cin) {
    __shared__ float t[32][33];
    const int c0 = blockIdx.x * 32, r0 = blockIdx.y * 32;
    const int tx = threadIdx.x, ty = threadIdx.y;
    #pragma unroll
    for (int j = 0; j < 32; j += 8)
        t[ty + j][tx] = in[(size_t)(r0 + ty + j) * Cin + c0 + tx];
    __syncthreads();
    #pragma unroll
    for (int j = 0; j < 32; j += 8)
        out[(size_t)(c0 + ty + j) * R + r0 + tx] = f2bf(t[tx][ty + j]);
}

// ---------------- MFMA GEMM ----------------
// C[M][N] = A[M][K] @ B^T[N][K] (+bias, relu, poly-A, bf16-out as templated).
// 256 threads = 4 waves; wave grid (BM/WTM) x (BN/WTN); 16x16x32 bf16 MFMA.
// LDS layout: T[row][slot*8..] bf16, content k-chunk = slot ^ ((row>>2)&3)  (swizzle
// makes both global_load_lds lane order AND fragment ds_read_b128 conflict-free).

template<int BM, int BN, int WTM, int WTN, int K, int LDA, int LDB, int LDC,
         bool POLY, bool RELU, bool BIAS, bool OUTBF>
__global__ __launch_bounds__(256)
void mfma_gemm(const u16* __restrict__ A, const u16* __restrict__ B,
               const float* __restrict__ bias, const float* __restrict__ coeffs,
               void* __restrict__ Cv, const float* __restrict__ Aq)
{
    constexpr int MT = WTM / 16, NT = WTN / 16, GM = BM / WTM;
    __shared__ u16 As[BM * 32];
    __shared__ u16 Bs[BN * 32];

    const int tid = threadIdx.x;
    const int w = tid >> 6, lane = tid & 63;
    const int lrow = lane >> 2, lslot = lane & 3;
    const int m16 = lane & 15, quad = lane >> 4;
    const int bm = blockIdx.x * BM, bn = blockIdx.y * BN;
    const int wr = (w % GM) * WTM, wc = (w / GM) * WTN;

    float c0 = 0.f, c1 = 0.f, c2 = 0.f, c3 = 0.f;
    if constexpr (POLY) { c0 = coeffs[0]; c1 = coeffs[1]; c2 = coeffs[2]; c3 = coeffs[3]; }

    f32x4 acc[MT][NT];
    #pragma unroll
    for (int i = 0; i < MT; ++i)
        #pragma unroll
        for (int j = 0; j < NT; ++j)
            acc[i][j] = (f32x4){0.f, 0.f, 0.f, 0.f};

    for (int k0 = 0; k0 < K; k0 += 32) {
        // ---- stage B (global_load_lds, 16B/lane) ----
        #pragma unroll
        for (int i = 0; i < BN / 64; ++i) {
            const int row = (w * (BN / 64) + i) * 16 + lrow;
            const int c = lslot ^ ((row >> 2) & 3);
            gl2lds16(B + (size_t)(bn + row) * LDB + k0 + c * 8,
                     &Bs[row * 32 + lslot * 8]);
        }
        // ---- stage A ----
        #pragma unroll
        for (int i = 0; i < BM / 64; ++i) {
            const int row = (w * (BM / 64) + i) * 16 + lrow;
            const int c = lslot ^ ((row >> 2) & 3);
            if constexpr (POLY) {
                const int oct = k0 >> 6, d0 = k0 & 63;
                const float* qp = Aq + (size_t)(bm + row) * LDA + d0 + c * 8;
                const float4 v0 = *reinterpret_cast<const float4*>(qp);
                const float4 v1 = *reinterpret_cast<const float4*>(qp + 4);
                const float xs[8] = {v0.x, v0.y, v0.z, v0.w, v1.x, v1.y, v1.z, v1.w};
                const float coef = (oct == 0) ? c0 : (oct == 1) ? c1 : (oct == 2) ? c2 : c3;
                short8 sv;
                #pragma unroll
                for (int j = 0; j < 8; ++j) {
                    float p;
                    if (oct == 0) {
                        p = c0;
                    } else {
                        const float x = fminf(fmaxf(xs[j], -10.f), 10.f);
                        float t = x;
                        if (oct >= 2) t *= x;
                        if (oct == 3) t *= x;
                        p = fminf(fmaxf(coef * t, -1e6f), 1e6f);
                    }
                    sv[j] = (short)f2bf(p);
                }
                *reinterpret_cast<short8*>(&As[row * 32 + lslot * 8]) = sv;
            } else {
                gl2lds16(A + (size_t)(bm + row) * LDA + k0 + c * 8,
                         &As[row * 32 + lslot * 8]);
            }
        }
        __syncthreads();

        // ---- fragments + 16 MFMAs ----
        short8 af[MT], bf[NT];
        #pragma unroll
        for (int i = 0; i < MT; ++i) {
            const int row = wr + i * 16 + m16;
            const int s = quad ^ ((row >> 2) & 3);
            af[i] = *reinterpret_cast<const short8*>(&As[row * 32 + s * 8]);
        }
        #pragma unroll
        for (int j = 0; j < NT; ++j) {
            const int row = wc + j * 16 + m16;
            const int s = quad ^ ((row >> 2) & 3);
            bf[j] = *reinterpret_cast<const short8*>(&Bs[row * 32 + s * 8]);
        }
        #pragma unroll
        for (int i = 0; i < MT; ++i)
            #pragma unroll
            for (int j = 0; j < NT; ++j)
                acc[i][j] = __builtin_amdgcn_mfma_f32_16x16x32_bf16(
                    af[i], bf[j], acc[i][j], 0, 0, 0);
        __syncthreads();
    }

    // ---- epilogue: C[row = quad*4+reg][col = lane&15] per 16x16 tile ----
    #pragma unroll
    for (int j = 0; j < NT; ++j) {
        const int col = bn + wc + j * 16 + m16;
        float bv = 0.f;
        if constexpr (BIAS) bv = bias[col];
        #pragma unroll
        for (int i = 0; i < MT; ++i) {
            #pragma unroll
            for (int r = 0; r < 4; ++r) {
                const int row = bm + wr + i * 16 + quad * 4 + r;
                float v = acc[i][j][r] + bv;
                if constexpr (RELU) v = fmaxf(v, 0.f);
                if constexpr (OUTBF)
                    ((u16*)Cv)[(size_t)row * LDC + col] = f2bf(v);
                else
                    ((float*)Cv)[(size_t)row * LDC + col] = v;
            }
        }
    }
}

// ---------------- host ----------------

extern "C" void kernel_launch(void* const* d_in, const int* in_sizes, int n_in,
                              void* d_out, int out_size, void* d_ws, size_t ws_size,
                              hipStream_t stream) {
    const float* X      = (const float*)d_in[0];
    const float* Wq     = (const float*)d_in[1];
    const float* coeffs = (const float*)d_in[2];
    const float* W1     = (const float*)d_in[3];
    const float* b1     = (const float*)d_in[4];
    const float* W2     = (const float*)d_in[5];
    const float* b2     = (const float*)d_in[6];
    float* out = (float*)d_out;            // q staging (fp32) then final out

    char* ws = (char*)d_ws;
    u16* Xb  = (u16*)(ws);
    u16* Wqb = (u16*)(ws + 12582912);
    u16* W1b = (u16*)(ws + 13762560);
    u16* W2b = (u16*)(ws + 14024704);
    u16* Hb  = (u16*)(ws + 14090240);
    const size_t reserved = 14090240;

    // converts
    cast_f32_bf16<<<6144, 256, 0, stream>>>(X, Xb, 8192 * 768 / 4);
    transpose_cast<<<dim3(24, 24), dim3(32, 8), 0, stream>>>(Wq, Wqb, 768, 768);
    transpose_cast<<<dim3(16, 8),  dim3(32, 8), 0, stream>>>(W1, W1b, 256, 512);
    transpose_cast<<<dim3(2, 16),  dim3(32, 8), 0, stream>>>(W2, W2b, 512, 256);

    // GEMM1: q = Xb @ Wqb^T -> fp32 in d_out. M=8192 N=768 K=768.
    mfma_gemm<128, 128, 64, 64, 768, 768, 768, 768, false, false, false, false>
        <<<dim3(64, 6), 256, 0, stream>>>(Xb, Wqb, nullptr, nullptr, out, nullptr);

    const long ROWS = 98304;
    long ch = (long)((ws_size > reserved ? ws_size - reserved : 0) / 1024); // 512 bf16/row
    ch &= ~127L;
    if (ch > ROWS) ch = ROWS;
    if (ch < 128) ch = 128;

    for (long r0 = 0; r0 < ROWS; r0 += ch) {
        const long rows = (ROWS - r0 < ch) ? (ROWS - r0) : ch;
        // GEMM2: Hb = relu(poly(q) @ W1b^T + b1), bf16 out. M=rows N=512 K=256.
        mfma_gemm<128, 128, 64, 64, 256, 64, 256, 512, true, true, true, true>
            <<<dim3(rows / 128, 4), 256, 0, stream>>>(
                nullptr, W1b, b1, coeffs, Hb, out + r0 * 64);
        // GEMM3: out = Hb @ W2b^T + b2, fp32. M=rows N=64 K=512.
        mfma_gemm<128, 64, 32, 64, 512, 512, 512, 64, false, false, true, false>
            <<<dim3(rows / 128, 1), 256, 0, stream>>>(
                Hb, W2b, b2, nullptr, out + r0 * 64, nullptr);
    }
}